// Round 1
// baseline (1421.692 us; speedup 1.0000x reference)
//
#include <hip/hip_runtime.h>
#include <hip/hip_cooperative_groups.h>

namespace cg = cooperative_groups;

#define NN    8192
#define NL    16
#define NE    (NN * 128)
#define NOUTC 16
#define EOUTC (NN * NOUTC)

#define NBLK 256
#define NTHR 512
#define NTOT (NBLK * NTHR)

__device__ __forceinline__ float lrelu(float v) { return v >= 0.f ? v : 0.01f * v; }

__global__ __launch_bounds__(NTHR) void nn_kernel(
    const float* __restrict__ x,
    const float* __restrict__ edge_w,
    const int*   __restrict__ edge_src,
    const int*   __restrict__ edge_dst,
    const float* __restrict__ out_w,
    const int*   __restrict__ out_src,
    const int*   __restrict__ out_dst,
    float* __restrict__ acc,     // NL * NN floats (per-layer accumulators)
    float* __restrict__ outacc,  // NOUTC floats
    float* __restrict__ out)     // NOUTC floats (d_out)
{
    cg::grid_group grid = cg::this_grid();
    __shared__ float lds_vals[NN];
    __shared__ float out_bins[NOUTC];

    const int tidb = threadIdx.x;
    const int gtid = blockIdx.x * NTHR + tidb;

    // ---- phase 0: zero all accumulators (ws is poisoned 0xAA) ----
    for (int i = gtid; i < NL * NN; i += NTOT) acc[i] = 0.f;
    if (gtid < NOUTC) outacc[gtid] = 0.f;
    grid.sync();

    // ---- hidden layers ----
    for (int l = 0; l < NL; ++l) {
        // stage source values into LDS (lrelu applied lazily for l>0; layer 0 reads raw x)
        const float* sv = (l == 0) ? x : (acc + (size_t)(l - 1) * NN);
        for (int i = tidb * 4; i < NN; i += NTHR * 4) {
            float4 v = *(const float4*)(sv + i);
            if (l > 0) {
                v.x = lrelu(v.x); v.y = lrelu(v.y);
                v.z = lrelu(v.z); v.w = lrelu(v.w);
            }
            *(float4*)(lds_vals + i) = v;
        }
        __syncthreads();

        const int*   es = edge_src + (size_t)l * NE;
        const int*   ed = edge_dst + (size_t)l * NE;
        const float* ew = edge_w  + (size_t)l * NE;
        float* accL = acc + (size_t)l * NN;

        // NE / (NTOT*4) = 2 full iterations, no remainder
        for (int e = gtid * 4; e < NE; e += NTOT * 4) {
            int4   s = *(const int4*)(es + e);
            int4   d = *(const int4*)(ed + e);
            float4 w = *(const float4*)(ew + e);
            atomicAdd(accL + d.x, lds_vals[s.x] * w.x);
            atomicAdd(accL + d.y, lds_vals[s.y] * w.y);
            atomicAdd(accL + d.z, lds_vals[s.z] * w.z);
            atomicAdd(accL + d.w, lds_vals[s.w] * w.w);
        }
        grid.sync();
    }

    // ---- output layer ----
    {
        const float* sv = acc + (size_t)(NL - 1) * NN;
        for (int i = tidb * 4; i < NN; i += NTHR * 4) {
            float4 v = *(const float4*)(sv + i);
            v.x = lrelu(v.x); v.y = lrelu(v.y);
            v.z = lrelu(v.z); v.w = lrelu(v.w);
            *(float4*)(lds_vals + i) = v;
        }
        if (tidb < NOUTC) out_bins[tidb] = 0.f;
        __syncthreads();

        // EOUTC == NTOT: exactly one edge per thread
        for (int e = gtid; e < EOUTC; e += NTOT) {
            atomicAdd(&out_bins[out_dst[e]], lds_vals[out_src[e]] * out_w[e]);
        }
        __syncthreads();
        if (tidb < NOUTC) atomicAdd(&outacc[tidb], out_bins[tidb]);
    }
    grid.sync();

    // ---- softmax over 16 outputs (block 0, first wave) ----
    if (blockIdx.x == 0 && tidb < 64) {
        const int lane = tidb;
        float v = (lane < NOUTC) ? lrelu(outacc[lane]) : -INFINITY;
        float m = v;
        #pragma unroll
        for (int off = 32; off >= 1; off >>= 1)
            m = fmaxf(m, __shfl_xor(m, off, 64));
        float e = (lane < NOUTC) ? __expf(v - m) : 0.f;
        float s = e;
        #pragma unroll
        for (int off = 32; off >= 1; off >>= 1)
            s += __shfl_xor(s, off, 64);
        if (lane < NOUTC) out[lane] = e / s;
    }
}

extern "C" void kernel_launch(void* const* d_in, const int* in_sizes, int n_in,
                              void* d_out, int out_size, void* d_ws, size_t ws_size,
                              hipStream_t stream) {
    const float* x        = (const float*)d_in[0];
    const float* edge_w   = (const float*)d_in[1];
    const float* out_w    = (const float*)d_in[2];
    const int*   edge_src = (const int*)d_in[3];
    const int*   edge_dst = (const int*)d_in[4];
    const int*   out_src  = (const int*)d_in[5];
    const int*   out_dst  = (const int*)d_in[6];

    float* acc    = (float*)d_ws;              // NL*NN floats
    float* outacc = acc + (size_t)NL * NN;     // NOUTC floats
    float* out    = (float*)d_out;

    void* args[] = { &x, &edge_w, &edge_src, &edge_dst,
                     &out_w, &out_src, &out_dst,
                     &acc, &outacc, &out };

    hipLaunchCooperativeKernel((const void*)nn_kernel,
                               dim3(NBLK), dim3(NTHR),
                               args, 0, stream);
}

// Round 2
// 1335.763 us; speedup vs baseline: 1.0643x; 1.0643x over previous
//
#include <hip/hip_runtime.h>
#include <hip/hip_cooperative_groups.h>

namespace cg = cooperative_groups;

#define NN    8192
#define NL    16
#define NE    (NN * 128)
#define NOUTC 16
#define EOUTC (NN * NOUTC)

#define NBLK 256
#define NTHR 512
#define NTOT (NBLK * NTHR)
#define EPB  (NE / NBLK)     // 4096 edges per block per layer

__device__ __forceinline__ float lrelu(float v) { return v >= 0.f ? v : 0.01f * v; }

__global__ __launch_bounds__(NTHR) void nn_kernel(
    const float* __restrict__ x,
    const float* __restrict__ edge_w,
    const int*   __restrict__ edge_src,
    const int*   __restrict__ edge_dst,
    const float* __restrict__ out_w,
    const int*   __restrict__ out_src,
    const int*   __restrict__ out_dst,
    float* __restrict__ accbuf,    // 2 * NN floats (ping-pong layer results, pre-activation)
    float* __restrict__ partials,  // NBLK * NN floats
    float* __restrict__ outs,      // NBLK * 16 floats
    float* __restrict__ out)       // NOUTC floats (d_out)
{
    cg::grid_group grid = cg::this_grid();
    __shared__ float lds_vals[NN];   // activated source values (all 8192)
    __shared__ float lds_acc[NN];    // block-private accumulator
    __shared__ float sred[16][32];
    __shared__ float out_bins[NOUTC];

    const int b   = blockIdx.x;
    const int tid = threadIdx.x;

    // ================= hidden layers =================
    for (int l = 0; l < NL; ++l) {
        // ---- A: stage activated prev values into LDS, zero private acc ----
        const float* sv = (l == 0) ? x : (accbuf + (size_t)((l + 1) & 1) * NN);
        for (int i = tid * 4; i < NN; i += NTHR * 4) {
            float4 v = *(const float4*)(sv + i);
            if (l > 0) {
                v.x = lrelu(v.x); v.y = lrelu(v.y);
                v.z = lrelu(v.z); v.w = lrelu(v.w);
            }
            *(float4*)(lds_vals + i) = v;
            *(float4*)(lds_acc + i) = make_float4(0.f, 0.f, 0.f, 0.f);
        }
        __syncthreads();

        // ---- B: scatter this block's edge slice into private LDS acc ----
        {
            const size_t base = (size_t)l * NE + (size_t)b * EPB;
            const int* es = edge_src + base;
            const int* ed = edge_dst + base;
            const float* ew = edge_w + base;
            #pragma unroll
            for (int it = 0; it < EPB / (NTHR * 4); ++it) {
                const int e = tid * 4 + it * NTHR * 4;
                int4   s = *(const int4*)(es + e);
                int4   d = *(const int4*)(ed + e);
                float4 w = *(const float4*)(ew + e);
                atomicAdd(&lds_acc[d.x], lds_vals[s.x] * w.x);
                atomicAdd(&lds_acc[d.y], lds_vals[s.y] * w.y);
                atomicAdd(&lds_acc[d.z], lds_vals[s.z] * w.z);
                atomicAdd(&lds_acc[d.w], lds_vals[s.w] * w.w);
            }
        }
        __syncthreads();

        // ---- C: flush private acc to this block's partial row ----
        for (int i = tid * 4; i < NN; i += NTHR * 4)
            *(float4*)(partials + (size_t)b * NN + i) = *(const float4*)(lds_acc + i);
        grid.sync();

        // ---- D: reduce 256 partials for this block's 32 neurons ----
        {
            const int j  = tid >> 5;     // 0..15: which group of 16 partials
            const int nl = tid & 31;     // 0..31: neuron within block's span
            const int n  = b * 32 + nl;
            const float* pp = partials + (size_t)j * 16 * NN + n;
            float s = 0.f;
            #pragma unroll
            for (int k = 0; k < 16; ++k) s += pp[(size_t)k * NN];
            sred[j][nl] = s;
            __syncthreads();
            if (tid < 32) {
                float t = 0.f;
                #pragma unroll
                for (int j2 = 0; j2 < 16; ++j2) t += sred[j2][tid];
                accbuf[(size_t)(l & 1) * NN + b * 32 + tid] = t;  // pre-activation
            }
        }
        grid.sync();
    }

    // ================= output layer =================
    {
        const float* sv = accbuf + (size_t)((NL - 1) & 1) * NN;
        for (int i = tid * 4; i < NN; i += NTHR * 4) {
            float4 v = *(const float4*)(sv + i);
            v.x = lrelu(v.x); v.y = lrelu(v.y);
            v.z = lrelu(v.z); v.w = lrelu(v.w);
            *(float4*)(lds_vals + i) = v;
        }
        if (tid < NOUTC) out_bins[tid] = 0.f;
        __syncthreads();

        // EOUTC == NTOT: exactly one edge per thread
        const int g = b * NTHR + tid;
        const float contrib = lds_vals[out_src[g]] * out_w[g];
        atomicAdd(&out_bins[out_dst[g]], contrib);
        __syncthreads();
        if (tid < NOUTC) outs[(size_t)b * NOUTC + tid] = out_bins[tid];
    }
    grid.sync();

    // ================= final combine + softmax (block 0) =================
    if (b == 0) {
        if (tid < NOUTC) out_bins[tid] = 0.f;
        __syncthreads();
        if (tid < NBLK) {
            const float* rp = outs + (size_t)tid * NOUTC;
            #pragma unroll
            for (int j = 0; j < NOUTC; ++j) atomicAdd(&out_bins[j], rp[j]);
        }
        __syncthreads();
        if (tid < 64) {
            const int lane = tid;
            float v = (lane < NOUTC) ? lrelu(out_bins[lane]) : -INFINITY;
            float m = v;
            #pragma unroll
            for (int off = 32; off >= 1; off >>= 1)
                m = fmaxf(m, __shfl_xor(m, off, 64));
            float e = (lane < NOUTC) ? __expf(v - m) : 0.f;
            float s = e;
            #pragma unroll
            for (int off = 32; off >= 1; off >>= 1)
                s += __shfl_xor(s, off, 64);
            if (lane < NOUTC) out[lane] = e / s;
        }
    }
}

extern "C" void kernel_launch(void* const* d_in, const int* in_sizes, int n_in,
                              void* d_out, int out_size, void* d_ws, size_t ws_size,
                              hipStream_t stream) {
    const float* x        = (const float*)d_in[0];
    const float* edge_w   = (const float*)d_in[1];
    const float* out_w    = (const float*)d_in[2];
    const int*   edge_src = (const int*)d_in[3];
    const int*   edge_dst = (const int*)d_in[4];
    const int*   out_src  = (const int*)d_in[5];
    const int*   out_dst  = (const int*)d_in[6];

    float* accbuf   = (float*)d_ws;                         // 2*NN floats
    float* partials = accbuf + 2 * NN;                      // NBLK*NN floats (8 MB)
    float* outs     = partials + (size_t)NBLK * NN;         // NBLK*16 floats
    float* out      = (float*)d_out;

    void* args[] = { &x, &edge_w, &edge_src, &edge_dst,
                     &out_w, &out_src, &out_dst,
                     &accbuf, &partials, &outs, &out };

    hipLaunchCooperativeKernel((const void*)nn_kernel,
                               dim3(NBLK), dim3(NTHR),
                               args, 0, stream);
}

// Round 3
// 434.484 us; speedup vs baseline: 3.2721x; 3.0744x over previous
//
#include <hip/hip_runtime.h>

#define NN    8192
#define NL    16
#define NE    (NN * 128)
#define NOUTC 16
#define EOUTC (NN * NOUTC)

#define NBLK  256
#define NTHR  512
#define EPB   (NE / NBLK)     // 4096 edges per block per layer

__device__ __forceinline__ float lrelu(float v) { return v >= 0.f ? v : 0.01f * v; }

// ---- zero the layer accumulators + output accumulator ----
__global__ __launch_bounds__(256) void zero_kernel(float* __restrict__ p, int n) {
    int i = blockIdx.x * 256 + threadIdx.x;
    if (i < n) p[i] = 0.f;
}

// ---- one hidden layer: gather(LDS) -> scatter(LDS private acc) -> coalesced atomic flush ----
__global__ __launch_bounds__(NTHR) void layer_kernel(
    const float* __restrict__ sv,     // prev-layer pre-activation (or x)
    const int    apply_act,           // 0 for layer 0 (x is raw input)
    const int*   __restrict__ es,     // this layer's edge_src
    const int*   __restrict__ ed,     // this layer's edge_dst
    const float* __restrict__ ew,     // this layer's edge_w
    float*       __restrict__ accL)   // this layer's accumulator (pre-zeroed)
{
    __shared__ float vals[NN];   // activated source values
    __shared__ float accs[NN];   // block-private accumulator
    const int tid = threadIdx.x;
    const int b   = blockIdx.x;

    // stage full activated source vector into LDS; zero private acc
    for (int i = tid * 4; i < NN; i += NTHR * 4) {
        float4 v = *(const float4*)(sv + i);
        if (apply_act) {
            v.x = lrelu(v.x); v.y = lrelu(v.y);
            v.z = lrelu(v.z); v.w = lrelu(v.w);
        }
        *(float4*)(vals + i) = v;
        *(float4*)(accs + i) = make_float4(0.f, 0.f, 0.f, 0.f);
    }
    __syncthreads();

    // scatter this block's contiguous edge slice into the private LDS acc
    const int base = b * EPB;
    #pragma unroll
    for (int it = 0; it < EPB / (NTHR * 4); ++it) {   // 2 iterations
        const int e = base + it * NTHR * 4 + tid * 4;
        int4   s = *(const int4*)(es + e);
        int4   d = *(const int4*)(ed + e);
        float4 w = *(const float4*)(ew + e);
        atomicAdd(&accs[d.x], vals[s.x] * w.x);
        atomicAdd(&accs[d.y], vals[s.y] * w.y);
        atomicAdd(&accs[d.z], vals[s.z] * w.z);
        atomicAdd(&accs[d.w], vals[s.w] * w.w);
    }
    __syncthreads();

    // coalesced flush; skip exactly-zero slots (~61% with lambda = 0.5)
    for (int i = tid; i < NN; i += NTHR) {
        float v = accs[i];
        if (v != 0.f) atomicAdd(accL + i, v);
    }
}

// ---- output layer: 16 bins, one edge per thread ----
__global__ __launch_bounds__(NTHR) void out_kernel(
    const float* __restrict__ acc15,
    const int*   __restrict__ out_src,
    const int*   __restrict__ out_dst,
    const float* __restrict__ out_w,
    float*       __restrict__ outacc)   // pre-zeroed
{
    __shared__ float bins[NOUTC];
    const int tid = threadIdx.x;
    if (tid < NOUTC) bins[tid] = 0.f;
    __syncthreads();
    const int g = blockIdx.x * NTHR + tid;    // EOUTC == NBLK*NTHR exactly
    const float v = lrelu(acc15[out_src[g]]); // 32 KB hot region -> L1/L2 hits
    atomicAdd(&bins[out_dst[g]], v * out_w[g]);
    __syncthreads();
    if (tid < NOUTC) atomicAdd(&outacc[tid], bins[tid]);
}

// ---- lrelu + softmax over 16 outputs ----
__global__ __launch_bounds__(64) void softmax_kernel(
    const float* __restrict__ outacc, float* __restrict__ out)
{
    const int lane = threadIdx.x;
    float v = (lane < NOUTC) ? lrelu(outacc[lane]) : -INFINITY;
    float m = v;
    #pragma unroll
    for (int off = 32; off >= 1; off >>= 1)
        m = fmaxf(m, __shfl_xor(m, off, 64));
    float e = (lane < NOUTC) ? __expf(v - m) : 0.f;
    float s = e;
    #pragma unroll
    for (int off = 32; off >= 1; off >>= 1)
        s += __shfl_xor(s, off, 64);
    if (lane < NOUTC) out[lane] = e / s;
}

extern "C" void kernel_launch(void* const* d_in, const int* in_sizes, int n_in,
                              void* d_out, int out_size, void* d_ws, size_t ws_size,
                              hipStream_t stream) {
    const float* x        = (const float*)d_in[0];
    const float* edge_w   = (const float*)d_in[1];
    const float* out_w    = (const float*)d_in[2];
    const int*   edge_src = (const int*)d_in[3];
    const int*   edge_dst = (const int*)d_in[4];
    const int*   out_src  = (const int*)d_in[5];
    const int*   out_dst  = (const int*)d_in[6];

    float* acc    = (float*)d_ws;            // NL*NN floats (per-layer accumulators)
    float* outacc = acc + (size_t)NL * NN;   // NOUTC floats
    float* out    = (float*)d_out;

    // zero all accumulators (ws is poisoned 0xAA before every call)
    const int nz = NL * NN + NOUTC;
    zero_kernel<<<(nz + 255) / 256, 256, 0, stream>>>(acc, nz);

    // 16 hidden layers, chained by stream order
    for (int l = 0; l < NL; ++l) {
        const float* sv = (l == 0) ? x : (acc + (size_t)(l - 1) * NN);
        layer_kernel<<<NBLK, NTHR, 0, stream>>>(
            sv, l > 0,
            edge_src + (size_t)l * NE,
            edge_dst + (size_t)l * NE,
            edge_w   + (size_t)l * NE,
            acc + (size_t)l * NN);
    }

    out_kernel<<<NBLK, NTHR, 0, stream>>>(
        acc + (size_t)(NL - 1) * NN, out_src, out_dst, out_w, outacc);

    softmax_kernel<<<1, 64, 0, stream>>>(outacc, out);
}

// Round 4
// 401.635 us; speedup vs baseline: 3.5398x; 1.0818x over previous
//
#include <hip/hip_runtime.h>

#define NN    8192
#define NL    16
#define NE    (NN * 128)
#define NOUTC 16
#define EOUTC (NN * NOUTC)

#define NBLK  256
#define NTHR  512
#define EPB   (NE / NBLK)     // 4096 edges per block per layer

__device__ __forceinline__ float lrelu(float v) { return v >= 0.f ? v : 0.01f * v; }

// ---- scatter: gather(LDS) -> LDS private acc -> coalesced dense partial write ----
__global__ __launch_bounds__(NTHR) void scatter_kernel(
    const float* __restrict__ sv,       // activated source vector (x or accbuf)
    const int*   __restrict__ es,
    const int*   __restrict__ ed,
    const float* __restrict__ ew,
    float*       __restrict__ partials) // [NBLK][NN]
{
    __shared__ float vals[NN];
    __shared__ float accs[NN];
    const int tid = threadIdx.x;
    const int b   = blockIdx.x;

    for (int i = tid * 4; i < NN; i += NTHR * 4) {
        *(float4*)(vals + i) = *(const float4*)(sv + i);
        *(float4*)(accs + i) = make_float4(0.f, 0.f, 0.f, 0.f);
    }
    __syncthreads();

    const int base = b * EPB;
    #pragma unroll
    for (int it = 0; it < EPB / (NTHR * 4); ++it) {   // 2 iterations
        const int e = base + it * NTHR * 4 + tid * 4;
        int4   s = *(const int4*)(es + e);
        int4   d = *(const int4*)(ed + e);
        float4 w = *(const float4*)(ew + e);
        atomicAdd(&accs[d.x], vals[s.x] * w.x);
        atomicAdd(&accs[d.y], vals[s.y] * w.y);
        atomicAdd(&accs[d.z], vals[s.z] * w.z);
        atomicAdd(&accs[d.w], vals[s.w] * w.w);
    }
    __syncthreads();

    float* prow = partials + (size_t)b * NN;
    for (int i = tid * 4; i < NN; i += NTHR * 4)
        *(float4*)(prow + i) = *(const float4*)(accs + i);
}

// ---- reduce 256 partials -> activated layer vector ----
__global__ __launch_bounds__(256) void reduce_kernel(
    const float* __restrict__ partials,  // [NBLK][NN]
    float*       __restrict__ accv)      // [NN], activated
{
    __shared__ float sred[8][32];
    const int b  = blockIdx.x;           // 256 blocks, 32 neurons each
    const int nl = threadIdx.x & 31;
    const int kg = threadIdx.x >> 5;     // 0..7
    const int n  = b * 32 + nl;

    float s = 0.f;
    #pragma unroll
    for (int k = 0; k < NBLK / 8; ++k)
        s += partials[(size_t)(kg + k * 8) * NN + n];
    sred[kg][nl] = s;
    __syncthreads();
    if (threadIdx.x < 32) {
        float t = 0.f;
        #pragma unroll
        for (int j = 0; j < 8; ++j) t += sred[j][threadIdx.x];
        accv[b * 32 + threadIdx.x] = lrelu(t);
    }
}

// ---- output scatter: one edge per thread, 16 LDS bins -> outs[b][16] ----
__global__ __launch_bounds__(NTHR) void out_scatter_kernel(
    const float* __restrict__ accv,      // activated layer-15 vector
    const int*   __restrict__ out_src,
    const int*   __restrict__ out_dst,
    const float* __restrict__ out_w,
    float*       __restrict__ outs)      // [NBLK][NOUTC]
{
    __shared__ float bins[NOUTC];
    const int tid = threadIdx.x;
    if (tid < NOUTC) bins[tid] = 0.f;
    __syncthreads();
    const int g = blockIdx.x * NTHR + tid;          // EOUTC == NBLK*NTHR exactly
    atomicAdd(&bins[out_dst[g]], accv[out_src[g]] * out_w[g]);
    __syncthreads();
    if (tid < NOUTC) outs[(size_t)blockIdx.x * NOUTC + tid] = bins[tid];
}

// ---- final: reduce 256x16, lrelu, softmax ----
__global__ __launch_bounds__(256) void final_kernel(
    const float* __restrict__ outs, float* __restrict__ out)
{
    __shared__ float red[16][17];
    const int tid = threadIdx.x;
    const int j = tid & 15, g = tid >> 4;            // 16 groups x 16 bins
    float s = 0.f;
    #pragma unroll
    for (int r = 0; r < NBLK / 16; ++r)
        s += outs[(size_t)(g + r * 16) * NOUTC + j];
    red[g][j] = s;
    __syncthreads();
    if (tid < NOUTC) {
        float t = 0.f;
        #pragma unroll
        for (int g2 = 0; g2 < 16; ++g2) t += red[g2][tid];
        float v = lrelu(t);
        // softmax across lanes 0..15 (xor within low 4 bits stays in-group)
        float m = v;
        #pragma unroll
        for (int off = 8; off >= 1; off >>= 1)
            m = fmaxf(m, __shfl_xor(m, off, 64));
        float e = __expf(v - m);
        float ssum = e;
        #pragma unroll
        for (int off = 8; off >= 1; off >>= 1)
            ssum += __shfl_xor(ssum, off, 64);
        out[tid] = e / ssum;
    }
}

extern "C" void kernel_launch(void* const* d_in, const int* in_sizes, int n_in,
                              void* d_out, int out_size, void* d_ws, size_t ws_size,
                              hipStream_t stream) {
    const float* x        = (const float*)d_in[0];
    const float* edge_w   = (const float*)d_in[1];
    const float* out_w    = (const float*)d_in[2];
    const int*   edge_src = (const int*)d_in[3];
    const int*   edge_dst = (const int*)d_in[4];
    const int*   out_src  = (const int*)d_in[5];
    const int*   out_dst  = (const int*)d_in[6];

    float* partials = (float*)d_ws;                     // NBLK*NN floats (8 MB)
    float* accv     = partials + (size_t)NBLK * NN;     // NN floats
    float* outs     = accv + NN;                        // NBLK*NOUTC floats
    float* out      = (float*)d_out;

    for (int l = 0; l < NL; ++l) {
        const float* sv = (l == 0) ? x : accv;
        scatter_kernel<<<NBLK, NTHR, 0, stream>>>(
            sv,
            edge_src + (size_t)l * NE,
            edge_dst + (size_t)l * NE,
            edge_w   + (size_t)l * NE,
            partials);
        reduce_kernel<<<NBLK, 256, 0, stream>>>(partials, accv);
    }

    out_scatter_kernel<<<NBLK, NTHR, 0, stream>>>(accv, out_src, out_dst, out_w, outs);
    final_kernel<<<1, 256, 0, stream>>>(outs, out);
}